// Round 12
// baseline (143.855 us; speedup 1.0000x reference)
//
#include <hip/hip_runtime.h>
#include <hip/hip_bf16.h>
#include <math.h>

// HungarianMatcher cost matrix, round 11: fully-hoisted column slice.
// out[row, j] = sum_k |boxes[row][k] - tgt[j][k]| - sigmoid(logits[row])[ids[j]]
// out = [8192, 4096] f32 = 134 MB; write floor ~21 us @ 6.6 TB/s (fill-proven).
//
// Normalized ladder (dur_us minus harness fills): RPB=1 ~56 -> RPB=4 ~41 ->
// {RPB=8+nt, RPB=16+nt, RPB=8 plain} all 41 +/- 2 us. Read traffic, store
// cache policy, and block geometry are exhausted (null). Last mechanism:
// kill in-loop load latency entirely. Each wave owns a fixed 256-col slice
// (jc = w*256 + it*64 + lane); all 20 column loads are hoisted to registers
// before the row loop, so the steady loop is pure VALU + coalesced stores,
// and each wave's 4 stores per row form a 4 KB sequential run.

#define COLS   4096
#define COLS4  1024        // float4 columns
#define RPB    8           // rows per block
#define NIT    4           // 4 x 64-col groups per wave slice

typedef float f32x4 __attribute__((ext_vector_type(4)));

__device__ __forceinline__ float l1d(const float4 a, const float4 b) {
    return fabsf(a.x - b.x) + fabsf(a.y - b.y) +
           fabsf(a.z - b.z) + fabsf(a.w - b.w);
}

__global__ __launch_bounds__(256) void matcher_cost_kernel(
    const float* __restrict__ logits,   // [rows, 2]
    const float* __restrict__ boxes,    // [rows, 4]
    const float* __restrict__ tgt,      // [4096, 4]
    const int*   __restrict__ ids,      // [4096]
    float* __restrict__ out)            // [rows, 4096]
{
    const int tid  = threadIdx.x;
    const int lane = tid & 63;
    const int w    = tid >> 6;
    const int r0   = blockIdx.x * RPB;

    // Per-row constants: box float4, nb = -p0, dp = p0 - p1.
    //   cost = l1 - (id ? p1 : p0) = l1 + nb + sel*dp,  sel = (id != 0)
    float4 bx[RPB];
    float  nb[RPB], dp[RPB];
#pragma unroll
    for (int r = 0; r < RPB; ++r) {
        const int row = r0 + r;
        bx[r] = reinterpret_cast<const float4*>(boxes)[row];
        const float p0 = 1.0f / (1.0f + __expf(-logits[row * 2 + 0]));
        const float p1 = 1.0f / (1.0f + __expf(-logits[row * 2 + 1]));
        nb[r] = -p0;
        dp[r] = p0 - p1;
    }

    const float4* __restrict__ tgt4 = reinterpret_cast<const float4*>(tgt);
    const int4*   __restrict__ ids4 = reinterpret_cast<const int4*>(ids);
    f32x4* __restrict__ out4 = reinterpret_cast<f32x4*>(out);

    // Hoist the wave's whole column slice into registers (20 loads, max ILP).
    const int jcbase = w * 256 + lane;
    float4 t[NIT][4];
    float4 sel[NIT];
#pragma unroll
    for (int it = 0; it < NIT; ++it) {
        const int jc = jcbase + it * 64;
        const int jb = jc * 4;
        t[it][0] = tgt4[jb + 0];
        t[it][1] = tgt4[jb + 1];
        t[it][2] = tgt4[jb + 2];
        t[it][3] = tgt4[jb + 3];
        const int4 id4 = ids4[jc];
        sel[it].x = id4.x ? 1.0f : 0.0f;
        sel[it].y = id4.y ? 1.0f : 0.0f;
        sel[it].z = id4.z ? 1.0f : 0.0f;
        sel[it].w = id4.w ? 1.0f : 0.0f;
    }

    // Steady loop: pure VALU + coalesced stores; per wave each row is a
    // 4 KB sequential run (4 x 1 KB back-to-back store instructions).
#pragma unroll
    for (int r = 0; r < RPB; ++r) {
        f32x4* __restrict__ orow = out4 + (size_t)(r0 + r) * COLS4;
#pragma unroll
        for (int it = 0; it < NIT; ++it) {
            f32x4 res;
            res.x = fmaf(sel[it].x, dp[r], l1d(bx[r], t[it][0]) + nb[r]);
            res.y = fmaf(sel[it].y, dp[r], l1d(bx[r], t[it][1]) + nb[r]);
            res.z = fmaf(sel[it].z, dp[r], l1d(bx[r], t[it][2]) + nb[r]);
            res.w = fmaf(sel[it].w, dp[r], l1d(bx[r], t[it][3]) + nb[r]);
            orow[jcbase + it * 64] = res;
        }
    }
}

extern "C" void kernel_launch(void* const* d_in, const int* in_sizes, int n_in,
                              void* d_out, int out_size, void* d_ws, size_t ws_size,
                              hipStream_t stream) {
    const float* logits = (const float*)d_in[0];   // pred_logits  [8,1024,2]
    const float* boxes  = (const float*)d_in[1];   // pred_boxes   [8,1024,4]
    const float* tgt    = (const float*)d_in[2];   // tgt_pts      [8,512,2,2]
    const int*   ids    = (const int*)d_in[3];     // tgt_labels   [8,512]
    float* out = (float*)d_out;

    const int rows = in_sizes[1] / 4;              // bs*Q = 8192
    matcher_cost_kernel<<<rows / RPB, 256, 0, stream>>>(logits, boxes, tgt, ids, out);
}